// Round 8
// baseline (1030.782 us; speedup 1.0000x reference)
//
#include <hip/hip_runtime.h>

#define N_V   11965
#define N_HE  189
#define NPAIR 35895
#define BB    256
#define SS    400
#define DD    128
#define BSR   102400   // B*S rows

typedef __bf16 bf16x8 __attribute__((ext_vector_type(8)));
typedef float  f32x4  __attribute__((ext_vector_type(4)));

__device__ __forceinline__ ushort f2bf(float f) {
    unsigned x = __float_as_uint(f);
    return (ushort)((x + 0x7FFFu + ((x >> 16) & 1u)) >> 16);
}
__device__ __forceinline__ float bf2f(ushort u) { return __uint_as_float(((unsigned)u) << 16); }
__device__ __forceinline__ float sigm(float x) { return 1.f / (1.f + __expf(-x)); }
__device__ __forceinline__ float tanh_f(float x) { return 2.f * sigm(2.f * x) - 1.f; }
// packed-bf16 unpack: low half = shift; high half = reinterpret (junk low mantissa
// bits perturb products by ~2^-17 relative — negligible vs bf16's 2^-8 quantum).
__device__ __forceinline__ float blo(unsigned u) { return __uint_as_float(u << 16); }
__device__ __forceinline__ float bhi(unsigned u) { return __uint_as_float(u); }

// ---------------------------------------------------------------------------
// P1: fused prep — BN affine fold, e_deg count, weight transposes (fp32->bf16),
// per-table small GEMMs (edW/epW/cW/cdW/a_gi), pred_s dot folds. All fp32 in.
// ---------------------------------------------------------------------------
struct P1Args {
    const int* pair_e;
    const float *b1, *g1, *be1, *m1, *v1;
    const float *b2, *g2, *be2, *m2, *v2;
    const float *W1, *W2, *Wi, *Wg, *Ug;
    const float *ed_t, *ep_t, *c_t, *cd_t, *a_t, *bi, *bg;
    const float *ha_t, *ca_t, *as_t, *it_t, *Ws;
    int* e_deg;
    float* aff;          // s1[128], t1[128], s2[128], t2[128]
    ushort *W1T, *W2T, *WiTe, *WgT, *UgT;
    float *edW, *epW, *cW, *cdW, *agi, *sd;
};

__global__ __launch_bounds__(384) void p1_kernel(P1Args A) {
    int bid = blockIdx.x, t = threadIdx.x;
    if (bid == 0) {  // BN affine fold: BN(u) = u*s + (b*s + be - m*s)
        if (t < 128) {
            float s = A.g1[t] * rsqrtf(A.v1[t] + 1e-5f);
            A.aff[t] = s;
            A.aff[128 + t] = A.b1[t] * s + A.be1[t] - A.m1[t] * s;
        } else if (t < 256) {
            int d = t - 128;
            float s = A.g2[d] * rsqrtf(A.v2[d] + 1e-5f);
            A.aff[256 + d] = s;
            A.aff[384 + d] = A.b2[d] * s + A.be2[d] - A.m2[d] * s;
        }
        return;
    }
    bid -= 1;
    if (bid < 94) {  // e_deg count
        int p = bid * 384 + t;
        if (p < NPAIR) atomicAdd(&A.e_deg[A.pair_e[p]], 1);
        return;
    }
    bid -= 94;
    if (bid < 43) {  // W1T[n][k] = bf16(W1[k][n])
        int i = bid * 384 + t;
        if (i < 16384) { int k = i >> 7, n = i & 127; A.W1T[n * 128 + k] = f2bf(A.W1[i]); }
        return;
    }
    bid -= 43;
    if (bid < 43) {  // W2T
        int i = bid * 384 + t;
        if (i < 16384) { int k = i >> 7, n = i & 127; A.W2T[n * 128 + k] = f2bf(A.W2[i]); }
        return;
    }
    bid -= 43;
    if (bid < 43) {  // WiTe (Wi rows 0..127)
        int i = bid * 384 + t;
        if (i < 16384) { int k = i >> 7, n = i & 127; A.WiTe[n * 128 + k] = f2bf(A.Wi[i]); }
        return;
    }
    bid -= 43;
    if (bid < 128) {  // WgT (Wg rows 0..127, N=384)
        int i = bid * 384 + t;
        if (i < 49152) { int k = i / 384, n = i % 384; A.WgT[n * 128 + k] = f2bf(A.Wg[i]); }
        return;
    }
    bid -= 128;
    if (bid < 128) {  // UgT[n][k] = bf16(Ug[k][n])  (Ug: 128x384)
        int i = bid * 384 + t;
        if (i < 49152) { int k = i / 384, n = i % 384; A.UgT[n * 128 + k] = f2bf(A.Ug[i]); }
        return;
    }
    bid -= 128;
    if (bid < 101) {  // edW = ed_table @ Wi[128:256] + bi
        if (t < 128) {
            float acc = 0.f;
            for (int k = 0; k < 128; ++k)
                acc += A.ed_t[bid * 128 + k] * A.Wi[(128 + k) * 128 + t];
            A.edW[bid * 128 + t] = acc + A.bi[t];
        }
        return;
    }
    bid -= 101;
    if (bid < 101) {  // epW = ep_table @ Wi[256:384]
        if (t < 128) {
            float acc = 0.f;
            for (int k = 0; k < 128; ++k)
                acc += A.ep_t[bid * 128 + k] * A.Wi[(256 + k) * 128 + t];
            A.epW[bid * 128 + t] = acc;
        }
        return;
    }
    bid -= 101;
    if (bid < 189) {  // cW = c_table @ Wi[384:512]
        if (t < 128) {
            float acc = 0.f;
            for (int k = 0; k < 128; ++k)
                acc += A.c_t[bid * 128 + k] * A.Wi[(384 + k) * 128 + t];
            A.cW[bid * 128 + t] = acc;
        }
        return;
    }
    bid -= 189;
    if (bid < 101) {  // cdW = cd_table @ Wi[512:640]
        if (t < 128) {
            float acc = 0.f;
            for (int k = 0; k < 128; ++k)
                acc += A.cd_t[bid * 128 + k] * A.Wi[(512 + k) * 128 + t];
            A.cdW[bid * 128 + t] = acc;
        }
        return;
    }
    bid -= 101;
    if (bid < 2) {  // a_gi = a_table @ Wg[128:256] + bg  (2 x 384)
        float acc = 0.f;
        for (int k = 0; k < 128; ++k)
            acc += A.a_t[bid * 128 + k] * A.Wg[(128 + k) * 384 + t];
        A.agi[bid * 384 + t] = acc + A.bg[t];
        return;
    }
    bid -= 2;
    {  // sdots: 38 blocks — per-table Ws dot folds
        int r = bid;
        const float* tab; int woff, row;
        if (r < 11)      { tab = A.ha_t; row = r;      woff = 0;   }
        else if (r < 22) { tab = A.ca_t; row = r - 11; woff = 128; }
        else if (r < 30) { tab = A.as_t; row = r - 22; woff = 256; }
        else             { tab = A.it_t; row = r - 30; woff = 384; }
        if (t < 64) {
            float p = tab[row * 128 + t] * A.Ws[woff + t]
                    + tab[row * 128 + 64 + t] * A.Ws[woff + 64 + t];
            #pragma unroll
            for (int o = 32; o > 0; o >>= 1) p += __shfl_xor(p, o);
            if (t == 0) A.sd[r] = p;
        }
    }
}

// fp32 -> bf16 convert (for e_table MFMA operand)
__global__ void cvt_kernel(const float* __restrict__ src, ushort* __restrict__ dst, int n) {
    int i = blockIdx.x * 256 + threadIdx.x;
    if (i < n) dst[i] = f2bf(src[i]);
}

// ---------------------------------------------------------------------------
// CSR build for edge->vertex gather (atomic-free edge means)
// ---------------------------------------------------------------------------
__global__ void csr_prefix(const int* __restrict__ e_deg, int* __restrict__ start) {
    __shared__ int sc[256];
    int t = threadIdx.x;
    int d = (t < N_HE) ? e_deg[t] : 0;
    sc[t] = d;
    __syncthreads();
    for (int off = 1; off < 256; off <<= 1) {
        int v = (t >= off) ? sc[t - off] : 0;
        __syncthreads();
        sc[t] += v;
        __syncthreads();
    }
    if (t < N_HE) start[t] = sc[t] - d;        // exclusive
    if (t == N_HE - 1) start[N_HE] = sc[t];    // total
}

__global__ void csr_fill(const int* __restrict__ pair_e, const int* __restrict__ pair_v,
                         const int* __restrict__ start, int* __restrict__ cursor,
                         int* __restrict__ list) {
    int p = blockIdx.x * 384 + threadIdx.x;
    if (p >= NPAIR) return;
    int e = pair_e[p];
    int pos = atomicAdd(&cursor[e], 1);
    list[start[e] + pos] = pair_v[p];
}

// ---------------------------------------------------------------------------
// Generic MFMA GEMM: out[M][N] = A[M][128] @ B[128][N], B given transposed
// (BT[n][k], bf16). Optional per-column affine (BN fold), per-row a_gi add.
// ---------------------------------------------------------------------------
template <int NT>
__global__ __launch_bounds__(256) void gemm_mfma(
    const ushort* __restrict__ Amat, const ushort* __restrict__ BT,
    float* __restrict__ out, int M,
    const float* __restrict__ colS, const float* __restrict__ colB,
    const float* __restrict__ agi, const int* __restrict__ aidx) {
    const int N = NT * 16;
    int lane = threadIdx.x & 63, wave = threadIdx.x >> 6;
    int q = lane >> 4, c = lane & 15;
    int rowbase = blockIdx.x * 64 + wave * 16;
    int arow = rowbase + c;
    if (arow > M - 1) arow = M - 1;  // clamp A loads; stores guarded
    f32x4 acc[NT];
#pragma unroll
    for (int i = 0; i < NT; ++i) acc[i] = (f32x4){0.f, 0.f, 0.f, 0.f};
#pragma unroll
    for (int ko = 0; ko < 4; ++ko) {
        bf16x8 af = *(const bf16x8*)(Amat + (size_t)arow * 128 + ko * 32 + q * 8);
#pragma unroll
        for (int nt = 0; nt < NT; ++nt) {
            bf16x8 bfr = *(const bf16x8*)(BT + (size_t)(nt * 16 + c) * 128 + ko * 32 + q * 8);
            acc[nt] = __builtin_amdgcn_mfma_f32_16x16x32_bf16(af, bfr, acc[nt], 0, 0, 0);
        }
    }
#pragma unroll
    for (int nt = 0; nt < NT; ++nt) {
        int col = nt * 16 + c;
        float s = colS ? colS[col] : 1.f;
        float bb = colB ? colB[col] : 0.f;
#pragma unroll
        for (int r = 0; r < 4; ++r) {
            int row = rowbase + q * 4 + r;
            if (row < M) {
                float v = acc[nt][r] * s + bb;
                if (agi) v += agi[aidx[row] * N + col];
                out[(size_t)row * N + col] = v;
            }
        }
    }
}

// ---------------------------------------------------------------------------
// Hypergraph smoothing
// ---------------------------------------------------------------------------
__global__ __launch_bounds__(512) void edge_mean(const float* __restrict__ Y,
                                                 const int* __restrict__ list,
                                                 const int* __restrict__ start,
                                                 float* __restrict__ E) {
    __shared__ float red[4][128];
    int e = blockIdx.x;
    int d = threadIdx.x & 127, g = threadIdx.x >> 7;
    int s0 = start[e], n = start[e + 1] - s0;
    float acc = 0.f;
    for (int i = g; i < n; i += 4) acc += Y[(size_t)list[s0 + i] * DD + d];
    red[g][d] = acc;
    __syncthreads();
    if (g == 0) {
        float v = red[0][d] + red[1][d] + red[2][d] + red[3][d];
        E[e * DD + d] = v / (float)(n > 0 ? n : 1);
    }
}

__global__ void v_mean(const float* __restrict__ E, const int* __restrict__ pair_e,
                       ushort* __restrict__ Xo, int relu) {
    int idx = blockIdx.x * 256 + threadIdx.x;
    if (idx >= N_V * DD) return;
    int v = idx >> 7, d = idx & 127;
    float a = E[pair_e[3 * v] * DD + d] + E[pair_e[3 * v + 1] * DD + d] +
              E[pair_e[3 * v + 2] * DD + d];
    a *= (1.f / 3.f);
    if (relu) a = fmaxf(a, 0.f);
    Xo[idx] = f2bf(a);
}

// ---------------------------------------------------------------------------
// K3: x = tanh(XW[e] + cW[ec[e]] + cdW[ecd[e]] + edW[ed] + epW[ep]) -> bf16
// ---------------------------------------------------------------------------
__global__ void k3_kernel(const int* __restrict__ in_e, const int* __restrict__ in_ed,
                          const int* __restrict__ in_ep, const float* __restrict__ XW,
                          const float* __restrict__ cW, const float* __restrict__ cdW,
                          const float* __restrict__ edW, const float* __restrict__ epW,
                          const int* __restrict__ ec_map, const int* __restrict__ ecd_map,
                          ushort* __restrict__ xbf) {
    int idx = blockIdx.x * 256 + threadIdx.x;
    if (idx >= BSR * DD) return;
    int row = idx >> 7, d = idx & 127;
    int e = in_e[row];
    float v = XW[(size_t)e * DD + d] + cW[ec_map[e] * DD + d] + cdW[ecd_map[e] * DD + d] +
              edW[in_ed[row] * DD + d] + epW[in_ep[row] * DD + d];
    xbf[idx] = f2bf(tanh_f(v));
}

// ---------------------------------------------------------------------------
// pred_s head (fp32 out)
// ---------------------------------------------------------------------------
__global__ void pred_s_kernel(const int* __restrict__ ha, const int* __restrict__ ca,
                              const int* __restrict__ as_, const int* __restrict__ it,
                              const float* __restrict__ sd, const float* __restrict__ bs,
                              float* __restrict__ out) {
    int i = blockIdx.x * 256 + threadIdx.x;
    if (i >= BSR) return;
    float v = sd[ha[i]] + sd[11 + ca[i]] + sd[22 + as_[i]] + sd[30 + it[i]] + bs[0];
    out[i] = sigm(v);
}

// ---------------------------------------------------------------------------
// GRU scan v7: weights live in LDS (r3-r7 lesson: allocator clamps this
// kernel to <=68 VGPR; every register-residency scheme ended in scratch/L2
// refetch of 96 KB/step/CU = the invariant ~3050 cyc/step). LDS pipe serves
// the same stream at 85-128 B/cyc with ~6x lower latency. Layout: column
// stride 272 B (68 dw; 68 mod 32 = 4) -> consecutive lanes' b128 quads tile
// all 32 banks: zero excess conflict. 112 KB dynamic LDS (opt-in via
// hipFuncSetAttribute; gru_scan_glob is the automatic fallback).
// ---------------------------------------------------------------------------
#define WLDS_BYTES (384 * 272)                       // 104448
#define GRU_LDS_BYTES (WLDS_BYTES + (128 * 3 + 4 * 392) * 4)  // 112256

__global__ void
__attribute__((amdgpu_flat_work_group_size(768, 768)))
gru_scan_lds(
    const float* __restrict__ gi, const ushort* __restrict__ xb,
    const ushort* __restrict__ UgT, const float* __restrict__ h0,
    const float* __restrict__ We, const float* __restrict__ beo_p,
    float* __restrict__ out) {
    extern __shared__ __align__(16) char smem[];
    ushort* w_lds = (ushort*)smem;                       // 384 cols x 272 B
    float* h_s  = (float*)(smem + WLDS_BYTES);           // 128
    float* p_s  = h_s + 128;                             // 128
    float* n_sL = p_s + 128;                             // 128
    float* pp   = n_sL + 128;                            // 4 x 392
    int b = blockIdx.x, t = threadIdx.x;
    int kq = t / 192;          // wave-uniform K-quarter (192 = 3 waves)
    int cp = t % 192;          // columns cp and cp+192
    // stage UgT -> LDS, swizzled: 16B-unit idx -> col c = idx/16, u = idx%16,
    // dest unit = c*17 + u  (272 B = 17 units per column)
#pragma unroll
    for (int j = 0; j < 8; ++j) {
        int idx = j * 768 + t;                           // coalesced global read
        uint4 v = ((const uint4*)UgT)[idx];
        int c = idx >> 4, u = idx & 15;
        ((uint4*)w_lds)[c * 17 + u] = v;
    }
    const uint4* wA = (const uint4*)w_lds + cp * 17 + kq * 4;
    const uint4* wB = (const uint4*)w_lds + (cp + 192) * 17 + kq * 4;
    float beo = beo_p[0];
    float wev = 0.f;
    if (t < 128) { wev = We[t]; h_s[t] = h0[b * 128 + t]; }
    const float* gip = gi + (size_t)b * SS * 384;
    const ushort* xp = xb + (size_t)b * SS * 128;
    float gz_nx = 0.f, gr_nx = 0.f, gn_nx = 0.f, xw_nx = 0.f;
    if (t < 128) {
        gz_nx = gip[t];
        xw_nx = bf2f(xp[t]) * wev;
    } else if (t >= 256 && t < 384) {
        gr_nx = gip[t - 128];
        gn_nx = gip[t];
    }
    float* omain = out + BSR + b * SS;
    __syncthreads();
    for (int s = 0; s < SS; ++s) {
        float gz = gz_nx, gr = gr_nx, gn = gn_nx, xw = xw_nx;
        if (s + 1 < SS) {
            const float* g2 = gip + (size_t)(s + 1) * 384;
            if (t < 128) {
                gz_nx = g2[t];
                xw_nx = bf2f(xp[(size_t)(s + 1) * 128 + t]) * wev;
            } else if (t >= 256 && t < 384) {
                gr_nx = g2[t - 128];
                gn_nx = g2[t];
            }
        }
        // partial matvec: 2 cols x 32 k (own K-quarter); h via uniform b128,
        // weights via stride-68dw b128 (bank-tiling, conflict-free)
        const float4* h4 = (const float4*)h_s + kq * 8;
        float accA = 0.f, accB = 0.f;
#pragma unroll
        for (int i = 0; i < 4; ++i) {
            uint4 a = wA[i];
            uint4 c = wB[i];
            float4 hv0 = h4[2 * i], hv1 = h4[2 * i + 1];
            accA = fmaf(hv0.x, blo(a.x), accA); accA = fmaf(hv0.y, bhi(a.x), accA);
            accA = fmaf(hv0.z, blo(a.y), accA); accA = fmaf(hv0.w, bhi(a.y), accA);
            accA = fmaf(hv1.x, blo(a.z), accA); accA = fmaf(hv1.y, bhi(a.z), accA);
            accA = fmaf(hv1.z, blo(a.w), accA); accA = fmaf(hv1.w, bhi(a.w), accA);
            accB = fmaf(hv0.x, blo(c.x), accB); accB = fmaf(hv0.y, bhi(c.x), accB);
            accB = fmaf(hv0.z, blo(c.y), accB); accB = fmaf(hv0.w, bhi(c.y), accB);
            accB = fmaf(hv1.x, blo(c.z), accB); accB = fmaf(hv1.y, bhi(c.z), accB);
            accB = fmaf(hv1.z, blo(c.w), accB); accB = fmaf(hv1.w, bhi(c.w), accB);
        }
        pp[kq * 392 + cp] = accA;
        pp[kq * 392 + cp + 192] = accB;
        __syncthreads();
        float z = 0.f, h_old = 0.f;
        if (t < 128) {
            float S = pp[t] + pp[392 + t] + pp[784 + t] + pp[1176 + t];
            z = sigm(gz + S);
            h_old = h_s[t];
            p_s[t] = h_old * xw;
        } else if (t >= 256 && t < 384) {
            int j = t - 256;
            float Sr = pp[128 + j] + pp[392 + 128 + j] + pp[784 + 128 + j] + pp[1176 + 128 + j];
            float Sn = pp[256 + j] + pp[392 + 256 + j] + pp[784 + 256 + j] + pp[1176 + 256 + j];
            float r = sigm(gr + Sr);
            n_sL[j] = tanh_f(gn + r * Sn);
        }
        __syncthreads();
        if (t < 128) {
            h_s[t] = (1.f - z) * n_sL[t] + z * h_old;
        } else if (t >= 384 && t < 448) {  // wave 6: y reduction (pre-update h in p_s)
            int l = t - 384;
            float pv = p_s[l] + p_s[l + 64];
#pragma unroll
            for (int o = 32; o > 0; o >>= 1) pv += __shfl_xor(pv, o);
            if (l == 0) omain[s] = sigm(pv + beo);
        }
        __syncthreads();
    }
}

// ---------------------------------------------------------------------------
// Fallback (r7 kernel, global packed-uint weights) — used only if the
// dynamic-LDS opt-in is rejected by the runtime.
// ---------------------------------------------------------------------------
__global__ void
__attribute__((amdgpu_flat_work_group_size(768, 768)))
gru_scan_glob(
    const float* __restrict__ gi, const ushort* __restrict__ xb,
    const ushort* __restrict__ UgT, const float* __restrict__ h0,
    const float* __restrict__ We, const float* __restrict__ beo_p,
    float* __restrict__ out) {
    __shared__ __align__(16) float h_s[128];
    __shared__ float pp[4][392];
    __shared__ float n_sL[128];
    __shared__ float p_s[128];
    int b = blockIdx.x, t = threadIdx.x;
    int kq = t / 192;
    int cp = t % 192;
    const uint4* WA = (const uint4*)(UgT + (size_t)cp * 128 + kq * 32);
    const uint4* WB = (const uint4*)(UgT + (size_t)(cp + 192) * 128 + kq * 32);
    float beo = beo_p[0];
    float wev = 0.f;
    if (t < 128) { wev = We[t]; h_s[t] = h0[b * 128 + t]; }
    const float* gip = gi + (size_t)b * SS * 384;
    const ushort* xp = xb + (size_t)b * SS * 128;
    float gz_nx = 0.f, gr_nx = 0.f, gn_nx = 0.f, xw_nx = 0.f;
    if (t < 128) {
        gz_nx = gip[t];
        xw_nx = bf2f(xp[t]) * wev;
    } else if (t >= 256 && t < 384) {
        gr_nx = gip[t - 128];
        gn_nx = gip[t];
    }
    float* omain = out + BSR + b * SS;
    __syncthreads();
    for (int s = 0; s < SS; ++s) {
        float gz = gz_nx, gr = gr_nx, gn = gn_nx, xw = xw_nx;
        if (s + 1 < SS) {
            const float* g2 = gip + (size_t)(s + 1) * 384;
            if (t < 128) {
                gz_nx = g2[t];
                xw_nx = bf2f(xp[(size_t)(s + 1) * 128 + t]) * wev;
            } else if (t >= 256 && t < 384) {
                gr_nx = g2[t - 128];
                gn_nx = g2[t];
            }
        }
        const float4* h4 = (const float4*)h_s + kq * 8;
        float accA = 0.f, accB = 0.f;
#pragma unroll
        for (int i = 0; i < 4; ++i) {
            uint4 a = WA[i];
            uint4 c = WB[i];
            float4 hv0 = h4[2 * i], hv1 = h4[2 * i + 1];
            accA = fmaf(hv0.x, blo(a.x), accA); accA = fmaf(hv0.y, bhi(a.x), accA);
            accA = fmaf(hv0.z, blo(a.y), accA); accA = fmaf(hv0.w, bhi(a.y), accA);
            accA = fmaf(hv1.x, blo(a.z), accA); accA = fmaf(hv1.y, bhi(a.z), accA);
            accA = fmaf(hv1.z, blo(a.w), accA); accA = fmaf(hv1.w, bhi(a.w), accA);
            accB = fmaf(hv0.x, blo(c.x), accB); accB = fmaf(hv0.y, bhi(c.x), accB);
            accB = fmaf(hv0.z, blo(c.y), accB); accB = fmaf(hv0.w, bhi(c.y), accB);
            accB = fmaf(hv1.x, blo(c.z), accB); accB = fmaf(hv1.y, bhi(c.z), accB);
            accB = fmaf(hv1.z, blo(c.w), accB); accB = fmaf(hv1.w, bhi(c.w), accB);
        }
        pp[kq][cp] = accA;
        pp[kq][cp + 192] = accB;
        __syncthreads();
        float z = 0.f, h_old = 0.f;
        if (t < 128) {
            float S = pp[0][t] + pp[1][t] + pp[2][t] + pp[3][t];
            z = sigm(gz + S);
            h_old = h_s[t];
            p_s[t] = h_old * xw;
        } else if (t >= 256 && t < 384) {
            int j = t - 256;
            float Sr = pp[0][128 + j] + pp[1][128 + j] + pp[2][128 + j] + pp[3][128 + j];
            float Sn = pp[0][256 + j] + pp[1][256 + j] + pp[2][256 + j] + pp[3][256 + j];
            float r = sigm(gr + Sr);
            n_sL[j] = tanh_f(gn + r * Sn);
        }
        __syncthreads();
        if (t < 128) {
            h_s[t] = (1.f - z) * n_sL[t] + z * h_old;
        } else if (t >= 384 && t < 448) {
            int l = t - 384;
            float pv = p_s[l] + p_s[l + 64];
#pragma unroll
            for (int o = 32; o > 0; o >>= 1) pv += __shfl_xor(pv, o);
            if (l == 0) omain[s] = sigm(pv + beo);
        }
        __syncthreads();
    }
}

// ---------------------------------------------------------------------------
extern "C" void kernel_launch(void* const* d_in, const int* in_sizes, int n_in,
                              void* d_out, int out_size, void* d_ws, size_t ws_size,
                              hipStream_t stream) {
    const int* in_e   = (const int*)d_in[0];
    const int* in_ed  = (const int*)d_in[1];
    const int* in_ep  = (const int*)d_in[2];
    const int* in_a   = (const int*)d_in[3];
    const int* in_as  = (const int*)d_in[4];
    const int* in_ha  = (const int*)d_in[5];
    const int* in_ca  = (const int*)d_in[6];
    const int* in_it  = (const int*)d_in[7];
    const float* deliver_h = (const float*)d_in[8];
    const int* pair_v = (const int*)d_in[9];
    const int* pair_e = (const int*)d_in[10];
    const int* ec_map = (const int*)d_in[11];
    const int* ecd_map= (const int*)d_in[12];
    const float* e_table  = (const float*)d_in[13];
    const float* c_table  = (const float*)d_in[14];
    const float* ed_table = (const float*)d_in[15];
    const float* cd_table = (const float*)d_in[16];
    const float* a_table  = (const float*)d_in[17];
    const float* it_table = (const float*)d_in[18];
    const float* ep_table = (const float*)d_in[19];
    const float* ha_table = (const float*)d_in[20];
    const float* ca_table = (const float*)d_in[21];
    const float* as_table = (const float*)d_in[22];
    const float* W1 = (const float*)d_in[23];
    const float* b1 = (const float*)d_in[24];
    const float* g1 = (const float*)d_in[25];
    const float* be1= (const float*)d_in[26];
    const float* m1 = (const float*)d_in[27];
    const float* v1 = (const float*)d_in[28];
    const float* W2 = (const float*)d_in[29];
    const float* b2 = (const float*)d_in[30];
    const float* g2 = (const float*)d_in[31];
    const float* be2= (const float*)d_in[32];
    const float* m2 = (const float*)d_in[33];
    const float* v2 = (const float*)d_in[34];
    const float* Wi = (const float*)d_in[35];
    const float* bi = (const float*)d_in[36];
    const float* Wg = (const float*)d_in[37];
    const float* Ug = (const float*)d_in[38];
    const float* bg = (const float*)d_in[39];
    const float* We = (const float*)d_in[40];
    const float* beo= (const float*)d_in[41];
    const float* Ws = (const float*)d_in[42];
    const float* bs = (const float*)d_in[43];
    float* out = (float*)d_out;
    char* ws = (char*)d_ws;

    size_t off = 0;
    auto alloc = [&](size_t bytes) { size_t o = off; off += (bytes + 255) & ~(size_t)255; return o; };
    size_t o_degcur = alloc(378 * 4);            // e_deg[189] + cursor[189]
    size_t o_start  = alloc(190 * 4);
    size_t o_list   = alloc((size_t)NPAIR * 4);
    size_t o_aff    = alloc(512 * 4);
    size_t o_W1T    = alloc(16384 * 2);
    size_t o_W2T    = alloc(16384 * 2);
    size_t o_WiTe   = alloc(16384 * 2);
    size_t o_WgT    = alloc(49152 * 2);
    size_t o_UgT    = alloc(49152 * 2);
    size_t o_edW    = alloc(101 * 128 * 4);
    size_t o_epW    = alloc(101 * 128 * 4);
    size_t o_cW     = alloc(189 * 128 * 4);
    size_t o_cdW    = alloc(101 * 128 * 4);
    size_t o_agi    = alloc(2 * 384 * 4);
    size_t o_sd     = alloc(38 * 4);
    size_t o_etb    = alloc((size_t)N_V * DD * 2);
    size_t o_E      = alloc((size_t)N_HE * DD * 4);
    size_t o_Y      = alloc((size_t)N_V * DD * 4);
    size_t o_X1     = alloc((size_t)N_V * DD * 2);
    size_t o_X2     = alloc((size_t)N_V * DD * 2);
    size_t o_XW     = alloc((size_t)N_V * DD * 4);
    size_t o_xbf    = alloc((size_t)BSR * DD * 2);
    size_t o_gi     = alloc((size_t)BSR * 384 * 4);

    int*    e_deg  = (int*)(ws + o_degcur);
    int*    cursor = e_deg + 189;
    int*    startp = (int*)(ws + o_start);
    int*    listp  = (int*)(ws + o_list);
    float*  aff    = (float*)(ws + o_aff);
    ushort* W1T    = (ushort*)(ws + o_W1T);
    ushort* W2T    = (ushort*)(ws + o_W2T);
    ushort* WiTe   = (ushort*)(ws + o_WiTe);
    ushort* WgT    = (ushort*)(ws + o_WgT);
    ushort* UgTp   = (ushort*)(ws + o_UgT);
    float*  edW    = (float*)(ws + o_edW);
    float*  epW    = (float*)(ws + o_epW);
    float*  cW     = (float*)(ws + o_cW);
    float*  cdW    = (float*)(ws + o_cdW);
    float*  agi    = (float*)(ws + o_agi);
    float*  sd     = (float*)(ws + o_sd);
    ushort* e_tb   = (ushort*)(ws + o_etb);
    float*  E      = (float*)(ws + o_E);
    float*  Y      = (float*)(ws + o_Y);
    ushort* X1b    = (ushort*)(ws + o_X1);
    ushort* X2b    = (ushort*)(ws + o_X2);
    float*  XW     = (float*)(ws + o_XW);
    ushort* xbf    = (ushort*)(ws + o_xbf);
    float*  gi     = (float*)(ws + o_gi);

    hipMemsetAsync(ws + o_degcur, 0, 378 * 4, stream);

    P1Args pa;
    pa.pair_e = pair_e;
    pa.b1 = b1; pa.g1 = g1; pa.be1 = be1; pa.m1 = m1; pa.v1 = v1;
    pa.b2 = b2; pa.g2 = g2; pa.be2 = be2; pa.m2 = m2; pa.v2 = v2;
    pa.W1 = W1; pa.W2 = W2; pa.Wi = Wi; pa.Wg = Wg; pa.Ug = Ug;
    pa.ed_t = ed_table; pa.ep_t = ep_table; pa.c_t = c_table; pa.cd_t = cd_table;
    pa.a_t = a_table; pa.bi = bi; pa.bg = bg;
    pa.ha_t = ha_table; pa.ca_t = ca_table; pa.as_t = as_table; pa.it_t = it_table; pa.Ws = Ws;
    pa.e_deg = e_deg; pa.aff = aff;
    pa.W1T = W1T; pa.W2T = W2T; pa.WiTe = WiTe; pa.WgT = WgT; pa.UgT = UgTp;
    pa.edW = edW; pa.epW = epW; pa.cW = cW; pa.cdW = cdW; pa.agi = agi; pa.sd = sd;
    p1_kernel<<<1012, 384, 0, stream>>>(pa);

    cvt_kernel<<<(N_V * DD + 255) / 256, 256, 0, stream>>>(e_table, e_tb, N_V * DD);
    csr_prefix<<<1, 256, 0, stream>>>(e_deg, startp);
    csr_fill<<<94, 384, 0, stream>>>(pair_e, pair_v, startp, cursor, listp);

    pred_s_kernel<<<(BSR + 255) / 256, 256, 0, stream>>>(in_ha, in_ca, in_as, in_it, sd, bs, out);

    // conv1: Y = BN1(e_table @ W1 + b1)
    gemm_mfma<8><<<(N_V + 63) / 64, 256, 0, stream>>>(e_tb, W1T, Y, N_V, aff, aff + 128,
                                                      nullptr, nullptr);
    edge_mean<<<N_HE, 512, 0, stream>>>(Y, listp, startp, E);
    v_mean<<<(N_V * DD + 255) / 256, 256, 0, stream>>>(E, pair_e, X1b, 1);
    // conv2
    gemm_mfma<8><<<(N_V + 63) / 64, 256, 0, stream>>>(X1b, W2T, Y, N_V, aff + 256, aff + 384,
                                                      nullptr, nullptr);
    edge_mean<<<N_HE, 512, 0, stream>>>(Y, listp, startp, E);
    v_mean<<<(N_V * DD + 255) / 256, 256, 0, stream>>>(E, pair_e, X2b, 0);
    // XW = X2 @ Wi_e
    gemm_mfma<8><<<(N_V + 63) / 64, 256, 0, stream>>>(X2b, WiTe, XW, N_V, nullptr, nullptr,
                                                      nullptr, nullptr);
    // x = tanh(5-way gather sum)
    k3_kernel<<<(BSR * DD + 255) / 256, 256, 0, stream>>>(in_e, in_ed, in_ep, XW, cW, cdW, edW,
                                                          epW, ec_map, ecd_map, xbf);
    // gi = x @ Wg_x + a_gi[input_a]
    gemm_mfma<24><<<BSR / 64, 256, 0, stream>>>(xbf, WgT, gi, BSR, nullptr, nullptr, agi, in_a);

    // GRU scan + pred_main: LDS-resident weights if the runtime allows 112 KB
    // dynamic LDS; otherwise the r7 global-weight fallback. Deterministic
    // per-process -> same work every call (graph-capture safe).
    hipError_t attr_ok = hipFuncSetAttribute(
        reinterpret_cast<const void*>(gru_scan_lds),
        hipFuncAttributeMaxDynamicSharedMemorySize, GRU_LDS_BYTES);
    if (attr_ok == hipSuccess) {
        gru_scan_lds<<<BB, 768, GRU_LDS_BYTES, stream>>>(gi, xbf, UgTp, deliver_h, We, beo, out);
    } else {
        gru_scan_glob<<<BB, 768, 0, stream>>>(gi, xbf, UgTp, deliver_h, We, beo, out);
    }
}

// Round 9
// 976.492 us; speedup vs baseline: 1.0556x; 1.0556x over previous
//
#include <hip/hip_runtime.h>

#define N_V   11965
#define N_HE  189
#define NPAIR 35895
#define BB    256
#define SS    400
#define DD    128
#define BSR   102400   // B*S rows

typedef __bf16 bf16x8 __attribute__((ext_vector_type(8)));
typedef float  f32x4  __attribute__((ext_vector_type(4)));

__device__ __forceinline__ ushort f2bf(float f) {
    unsigned x = __float_as_uint(f);
    return (ushort)((x + 0x7FFFu + ((x >> 16) & 1u)) >> 16);
}
__device__ __forceinline__ float bf2f(ushort u) { return __uint_as_float(((unsigned)u) << 16); }
__device__ __forceinline__ float sigm(float x) { return 1.f / (1.f + __expf(-x)); }
__device__ __forceinline__ float tanh_f(float x) { return 2.f * sigm(2.f * x) - 1.f; }
// packed-bf16 unpack: low half = shift; high half = reinterpret (junk low mantissa
// bits perturb products by ~2^-17 relative — negligible vs bf16's 2^-8 quantum).
__device__ __forceinline__ float blo(unsigned u) { return __uint_as_float(u << 16); }
__device__ __forceinline__ float bhi(unsigned u) { return __uint_as_float(u); }

// ---------------------------------------------------------------------------
// P1: fused prep — BN affine fold, e_deg count, weight transposes (fp32->bf16),
// per-table small GEMMs (edW/epW/cW/cdW/a_gi), pred_s dot folds. All fp32 in.
// ---------------------------------------------------------------------------
struct P1Args {
    const int* pair_e;
    const float *b1, *g1, *be1, *m1, *v1;
    const float *b2, *g2, *be2, *m2, *v2;
    const float *W1, *W2, *Wi, *Wg, *Ug;
    const float *ed_t, *ep_t, *c_t, *cd_t, *a_t, *bi, *bg;
    const float *ha_t, *ca_t, *as_t, *it_t, *Ws;
    int* e_deg;
    float* aff;          // s1[128], t1[128], s2[128], t2[128]
    ushort *W1T, *W2T, *WiTe, *WgT, *UgT;
    float *edW, *epW, *cW, *cdW, *agi, *sd;
};

__global__ __launch_bounds__(384) void p1_kernel(P1Args A) {
    int bid = blockIdx.x, t = threadIdx.x;
    if (bid == 0) {  // BN affine fold: BN(u) = u*s + (b*s + be - m*s)
        if (t < 128) {
            float s = A.g1[t] * rsqrtf(A.v1[t] + 1e-5f);
            A.aff[t] = s;
            A.aff[128 + t] = A.b1[t] * s + A.be1[t] - A.m1[t] * s;
        } else if (t < 256) {
            int d = t - 128;
            float s = A.g2[d] * rsqrtf(A.v2[d] + 1e-5f);
            A.aff[256 + d] = s;
            A.aff[384 + d] = A.b2[d] * s + A.be2[d] - A.m2[d] * s;
        }
        return;
    }
    bid -= 1;
    if (bid < 94) {  // e_deg count
        int p = bid * 384 + t;
        if (p < NPAIR) atomicAdd(&A.e_deg[A.pair_e[p]], 1);
        return;
    }
    bid -= 94;
    if (bid < 43) {  // W1T[n][k] = bf16(W1[k][n])
        int i = bid * 384 + t;
        if (i < 16384) { int k = i >> 7, n = i & 127; A.W1T[n * 128 + k] = f2bf(A.W1[i]); }
        return;
    }
    bid -= 43;
    if (bid < 43) {  // W2T
        int i = bid * 384 + t;
        if (i < 16384) { int k = i >> 7, n = i & 127; A.W2T[n * 128 + k] = f2bf(A.W2[i]); }
        return;
    }
    bid -= 43;
    if (bid < 43) {  // WiTe (Wi rows 0..127)
        int i = bid * 384 + t;
        if (i < 16384) { int k = i >> 7, n = i & 127; A.WiTe[n * 128 + k] = f2bf(A.Wi[i]); }
        return;
    }
    bid -= 43;
    if (bid < 128) {  // WgT (Wg rows 0..127, N=384)
        int i = bid * 384 + t;
        if (i < 49152) { int k = i / 384, n = i % 384; A.WgT[n * 128 + k] = f2bf(A.Wg[i]); }
        return;
    }
    bid -= 128;
    if (bid < 128) {  // UgT[n][k] = bf16(Ug[k][n])  (Ug: 128x384)
        int i = bid * 384 + t;
        if (i < 49152) { int k = i / 384, n = i % 384; A.UgT[n * 128 + k] = f2bf(A.Ug[i]); }
        return;
    }
    bid -= 128;
    if (bid < 101) {  // edW = ed_table @ Wi[128:256] + bi
        if (t < 128) {
            float acc = 0.f;
            for (int k = 0; k < 128; ++k)
                acc += A.ed_t[bid * 128 + k] * A.Wi[(128 + k) * 128 + t];
            A.edW[bid * 128 + t] = acc + A.bi[t];
        }
        return;
    }
    bid -= 101;
    if (bid < 101) {  // epW = ep_table @ Wi[256:384]
        if (t < 128) {
            float acc = 0.f;
            for (int k = 0; k < 128; ++k)
                acc += A.ep_t[bid * 128 + k] * A.Wi[(256 + k) * 128 + t];
            A.epW[bid * 128 + t] = acc;
        }
        return;
    }
    bid -= 101;
    if (bid < 189) {  // cW = c_table @ Wi[384:512]
        if (t < 128) {
            float acc = 0.f;
            for (int k = 0; k < 128; ++k)
                acc += A.c_t[bid * 128 + k] * A.Wi[(384 + k) * 128 + t];
            A.cW[bid * 128 + t] = acc;
        }
        return;
    }
    bid -= 189;
    if (bid < 101) {  // cdW = cd_table @ Wi[512:640]
        if (t < 128) {
            float acc = 0.f;
            for (int k = 0; k < 128; ++k)
                acc += A.cd_t[bid * 128 + k] * A.Wi[(512 + k) * 128 + t];
            A.cdW[bid * 128 + t] = acc;
        }
        return;
    }
    bid -= 101;
    if (bid < 2) {  // a_gi = a_table @ Wg[128:256] + bg  (2 x 384)
        float acc = 0.f;
        for (int k = 0; k < 128; ++k)
            acc += A.a_t[bid * 128 + k] * A.Wg[(128 + k) * 384 + t];
        A.agi[bid * 384 + t] = acc + A.bg[t];
        return;
    }
    bid -= 2;
    {  // sdots: 38 blocks — per-table Ws dot folds
        int r = bid;
        const float* tab; int woff, row;
        if (r < 11)      { tab = A.ha_t; row = r;      woff = 0;   }
        else if (r < 22) { tab = A.ca_t; row = r - 11; woff = 128; }
        else if (r < 30) { tab = A.as_t; row = r - 22; woff = 256; }
        else             { tab = A.it_t; row = r - 30; woff = 384; }
        if (t < 64) {
            float p = tab[row * 128 + t] * A.Ws[woff + t]
                    + tab[row * 128 + 64 + t] * A.Ws[woff + 64 + t];
            #pragma unroll
            for (int o = 32; o > 0; o >>= 1) p += __shfl_xor(p, o);
            if (t == 0) A.sd[r] = p;
        }
    }
}

// fp32 -> bf16 convert (for e_table MFMA operand)
__global__ void cvt_kernel(const float* __restrict__ src, ushort* __restrict__ dst, int n) {
    int i = blockIdx.x * 256 + threadIdx.x;
    if (i < n) dst[i] = f2bf(src[i]);
}

// ---------------------------------------------------------------------------
// CSR build for edge->vertex gather (atomic-free edge means)
// ---------------------------------------------------------------------------
__global__ void csr_prefix(const int* __restrict__ e_deg, int* __restrict__ start) {
    __shared__ int sc[256];
    int t = threadIdx.x;
    int d = (t < N_HE) ? e_deg[t] : 0;
    sc[t] = d;
    __syncthreads();
    for (int off = 1; off < 256; off <<= 1) {
        int v = (t >= off) ? sc[t - off] : 0;
        __syncthreads();
        sc[t] += v;
        __syncthreads();
    }
    if (t < N_HE) start[t] = sc[t] - d;        // exclusive
    if (t == N_HE - 1) start[N_HE] = sc[t];    // total
}

__global__ void csr_fill(const int* __restrict__ pair_e, const int* __restrict__ pair_v,
                         const int* __restrict__ start, int* __restrict__ cursor,
                         int* __restrict__ list) {
    int p = blockIdx.x * 384 + threadIdx.x;
    if (p >= NPAIR) return;
    int e = pair_e[p];
    int pos = atomicAdd(&cursor[e], 1);
    list[start[e] + pos] = pair_v[p];
}

// ---------------------------------------------------------------------------
// Generic MFMA GEMM: out[M][N] = A[M][128] @ B[128][N], B given transposed
// (BT[n][k], bf16). Optional per-column affine (BN fold), per-row a_gi add.
// ---------------------------------------------------------------------------
template <int NT>
__global__ __launch_bounds__(256) void gemm_mfma(
    const ushort* __restrict__ Amat, const ushort* __restrict__ BT,
    float* __restrict__ out, int M,
    const float* __restrict__ colS, const float* __restrict__ colB,
    const float* __restrict__ agi, const int* __restrict__ aidx) {
    const int N = NT * 16;
    int lane = threadIdx.x & 63, wave = threadIdx.x >> 6;
    int q = lane >> 4, c = lane & 15;
    int rowbase = blockIdx.x * 64 + wave * 16;
    int arow = rowbase + c;
    if (arow > M - 1) arow = M - 1;  // clamp A loads; stores guarded
    f32x4 acc[NT];
#pragma unroll
    for (int i = 0; i < NT; ++i) acc[i] = (f32x4){0.f, 0.f, 0.f, 0.f};
#pragma unroll
    for (int ko = 0; ko < 4; ++ko) {
        bf16x8 af = *(const bf16x8*)(Amat + (size_t)arow * 128 + ko * 32 + q * 8);
#pragma unroll
        for (int nt = 0; nt < NT; ++nt) {
            bf16x8 bfr = *(const bf16x8*)(BT + (size_t)(nt * 16 + c) * 128 + ko * 32 + q * 8);
            acc[nt] = __builtin_amdgcn_mfma_f32_16x16x32_bf16(af, bfr, acc[nt], 0, 0, 0);
        }
    }
#pragma unroll
    for (int nt = 0; nt < NT; ++nt) {
        int col = nt * 16 + c;
        float s = colS ? colS[col] : 1.f;
        float bb = colB ? colB[col] : 0.f;
#pragma unroll
        for (int r = 0; r < 4; ++r) {
            int row = rowbase + q * 4 + r;
            if (row < M) {
                float v = acc[nt][r] * s + bb;
                if (agi) v += agi[aidx[row] * N + col];
                out[(size_t)row * N + col] = v;
            }
        }
    }
}

// ---------------------------------------------------------------------------
// Hypergraph smoothing
// ---------------------------------------------------------------------------
__global__ __launch_bounds__(512) void edge_mean(const float* __restrict__ Y,
                                                 const int* __restrict__ list,
                                                 const int* __restrict__ start,
                                                 float* __restrict__ E) {
    __shared__ float red[4][128];
    int e = blockIdx.x;
    int d = threadIdx.x & 127, g = threadIdx.x >> 7;
    int s0 = start[e], n = start[e + 1] - s0;
    float acc = 0.f;
    for (int i = g; i < n; i += 4) acc += Y[(size_t)list[s0 + i] * DD + d];
    red[g][d] = acc;
    __syncthreads();
    if (g == 0) {
        float v = red[0][d] + red[1][d] + red[2][d] + red[3][d];
        E[e * DD + d] = v / (float)(n > 0 ? n : 1);
    }
}

__global__ void v_mean(const float* __restrict__ E, const int* __restrict__ pair_e,
                       ushort* __restrict__ Xo, int relu) {
    int idx = blockIdx.x * 256 + threadIdx.x;
    if (idx >= N_V * DD) return;
    int v = idx >> 7, d = idx & 127;
    float a = E[pair_e[3 * v] * DD + d] + E[pair_e[3 * v + 1] * DD + d] +
              E[pair_e[3 * v + 2] * DD + d];
    a *= (1.f / 3.f);
    if (relu) a = fmaxf(a, 0.f);
    Xo[idx] = f2bf(a);
}

// ---------------------------------------------------------------------------
// K3: x = tanh(XW[e] + cW[ec[e]] + cdW[ecd[e]] + edW[ed] + epW[ep]) -> bf16
// ---------------------------------------------------------------------------
__global__ void k3_kernel(const int* __restrict__ in_e, const int* __restrict__ in_ed,
                          const int* __restrict__ in_ep, const float* __restrict__ XW,
                          const float* __restrict__ cW, const float* __restrict__ cdW,
                          const float* __restrict__ edW, const float* __restrict__ epW,
                          const int* __restrict__ ec_map, const int* __restrict__ ecd_map,
                          ushort* __restrict__ xbf) {
    int idx = blockIdx.x * 256 + threadIdx.x;
    if (idx >= BSR * DD) return;
    int row = idx >> 7, d = idx & 127;
    int e = in_e[row];
    float v = XW[(size_t)e * DD + d] + cW[ec_map[e] * DD + d] + cdW[ecd_map[e] * DD + d] +
              edW[in_ed[row] * DD + d] + epW[in_ep[row] * DD + d];
    xbf[idx] = f2bf(tanh_f(v));
}

// ---------------------------------------------------------------------------
// pred_s head (fp32 out)
// ---------------------------------------------------------------------------
__global__ void pred_s_kernel(const int* __restrict__ ha, const int* __restrict__ ca,
                              const int* __restrict__ as_, const int* __restrict__ it,
                              const float* __restrict__ sd, const float* __restrict__ bs,
                              float* __restrict__ out) {
    int i = blockIdx.x * 256 + threadIdx.x;
    if (i >= BSR) return;
    float v = sd[ha[i]] + sd[11 + ca[i]] + sd[22 + as_[i]] + sd[30 + it[i]] + bs[0];
    out[i] = sigm(v);
}

// ---------------------------------------------------------------------------
// GRU scan v8: weights in AGPRs + 2-barrier step.
// r8 falsified the weight-bandwidth theory (LDS-resident weights: same 537 µs).
// The r2-r8 invariant tracks the VGPR clamp (<=68, now 40): the compiler
// serializes LDS/L2 loads through a tiny register window (load->waitcnt->use
// chains ~120cyc each = the ~3200cyc/step). Fix: (1) the 32 packed-bf16 weight
// uints live in AGPRs ("a" constraint) — per-step access is v_accvgpr_read,
// a register move, no memory, no lgkmcnt; (2) gates+update merged into one
// phase (t<128 computes z,r,n,h itself; h kept in a register), y-dot deferred
// one step to wave 11 during the matvec phase -> 2 barriers/step.
// ---------------------------------------------------------------------------
__global__ void
__attribute__((amdgpu_flat_work_group_size(768, 768)))
gru_scan(
    const float* __restrict__ gi, const ushort* __restrict__ xb,
    const ushort* __restrict__ UgT, const float* __restrict__ h0,
    const float* __restrict__ We, const float* __restrict__ beo_p,
    float* __restrict__ out) {
    __shared__ __align__(16) float h_s[128];
    __shared__ float p_s[128];
    __shared__ float pp[4][392];
    int b = blockIdx.x, t = threadIdx.x;
    int kq = t / 192;          // wave-uniform K-quarter (192 = 3 waves)
    int cp = t % 192;          // columns cp and cp+192
    const uint4* WA = (const uint4*)(UgT + (size_t)cp * 128 + kq * 32);
    const uint4* WB = (const uint4*)(UgT + (size_t)(cp + 192) * 128 + kq * 32);
    uint4 A0 = WA[0], A1 = WA[1], A2 = WA[2], A3 = WA[3];
    uint4 B0 = WB[0], B1 = WB[1], B2 = WB[2], B3 = WB[3];
    unsigned a0 = A0.x, a1 = A0.y, a2 = A0.z, a3 = A0.w;
    unsigned a4 = A1.x, a5 = A1.y, a6 = A1.z, a7 = A1.w;
    unsigned a8 = A2.x, a9 = A2.y, a10 = A2.z, a11 = A2.w;
    unsigned a12 = A3.x, a13 = A3.y, a14 = A3.z, a15 = A3.w;
    unsigned c0 = B0.x, c1 = B0.y, c2 = B0.z, c3 = B0.w;
    unsigned c4 = B1.x, c5 = B1.y, c6 = B1.z, c7 = B1.w;
    unsigned c8 = B2.x, c9 = B2.y, c10 = B2.z, c11 = B2.w;
    unsigned c12 = B3.x, c13 = B3.y, c14 = B3.z, c15 = B3.w;
    float beo = beo_p[0];
    float wev = 0.f, hreg = 0.f;
    if (t < 128) {
        wev = We[t];
        hreg = h0[b * 128 + t];
        h_s[t] = hreg;
    }
    const float* gip = gi + (size_t)b * SS * 384;
    const ushort* xp = xb + (size_t)b * SS * 128;
    float gz_nx = 0.f, gr_nx = 0.f, gn_nx = 0.f, xw_nx = 0.f;
    if (t < 128) {
        gz_nx = gip[t];
        gr_nx = gip[128 + t];
        gn_nx = gip[256 + t];
        xw_nx = bf2f(xp[t]) * wev;
    }
    float* omain = out + BSR + b * SS;
    __syncthreads();
    for (int s = 0; s < SS; ++s) {
        // AGPR residency pin: the 32 weight uints must be in AGPRs at every
        // iteration boundary; uses below read them via v_accvgpr_read.
#define PINA(X) asm volatile("" : "+a"(X));
        PINA(a0) PINA(a1) PINA(a2) PINA(a3) PINA(a4) PINA(a5) PINA(a6) PINA(a7)
        PINA(a8) PINA(a9) PINA(a10) PINA(a11) PINA(a12) PINA(a13) PINA(a14) PINA(a15)
        PINA(c0) PINA(c1) PINA(c2) PINA(c3) PINA(c4) PINA(c5) PINA(c6) PINA(c7)
        PINA(c8) PINA(c9) PINA(c10) PINA(c11) PINA(c12) PINA(c13) PINA(c14) PINA(c15)
#undef PINA
        float gz = gz_nx, gr = gr_nx, gn = gn_nx, xw = xw_nx;
        if (s + 1 < SS && t < 128) {
            const float* g2 = gip + (size_t)(s + 1) * 384;
            gz_nx = g2[t];
            gr_nx = g2[128 + t];
            gn_nx = g2[256 + t];
            xw_nx = bf2f(xp[(size_t)(s + 1) * 128 + t]) * wev;
        }
        // phase A: matvec (2 cols x 32 k, weights from AGPR, h broadcast)
        const float4* h4 = (const float4*)h_s + kq * 8;
        float accA = 0.f, accB = 0.f;
#define FB2(HI, U0, U1, U2, U3, V0, V1, V2, V3) { \
        float4 hv0 = h4[HI], hv1 = h4[HI + 1]; \
        accA = fmaf(hv0.x, blo(U0), accA); accA = fmaf(hv0.y, bhi(U0), accA); \
        accA = fmaf(hv0.z, blo(U1), accA); accA = fmaf(hv0.w, bhi(U1), accA); \
        accA = fmaf(hv1.x, blo(U2), accA); accA = fmaf(hv1.y, bhi(U2), accA); \
        accA = fmaf(hv1.z, blo(U3), accA); accA = fmaf(hv1.w, bhi(U3), accA); \
        accB = fmaf(hv0.x, blo(V0), accB); accB = fmaf(hv0.y, bhi(V0), accB); \
        accB = fmaf(hv0.z, blo(V1), accB); accB = fmaf(hv0.w, bhi(V1), accB); \
        accB = fmaf(hv1.x, blo(V2), accB); accB = fmaf(hv1.y, bhi(V2), accB); \
        accB = fmaf(hv1.z, blo(V3), accB); accB = fmaf(hv1.w, bhi(V3), accB); }
        FB2(0, a0, a1, a2, a3, c0, c1, c2, c3)
        FB2(2, a4, a5, a6, a7, c4, c5, c6, c7)
        FB2(4, a8, a9, a10, a11, c8, c9, c10, c11)
        FB2(6, a12, a13, a14, a15, c12, c13, c14, c15)
#undef FB2
        pp[kq][cp] = accA;
        pp[kq][cp + 192] = accB;
        // wave 11: deferred y for step s-1 (p_s staged last phase B; h,x pre-update)
        if (t >= 704 && s > 0) {
            int l = t - 704;
            float pv = p_s[l] + p_s[l + 64];
#pragma unroll
            for (int o = 32; o > 0; o >>= 1) pv += __shfl_xor(pv, o);
            if (l == 0) omain[s - 1] = sigm(pv + beo);
        }
        __syncthreads();
        // phase B: t<128 computes all three gates + h update (h in register)
        if (t < 128) {
            float Sz = pp[0][t] + pp[1][t] + pp[2][t] + pp[3][t];
            float Sr = pp[0][128 + t] + pp[1][128 + t] + pp[2][128 + t] + pp[3][128 + t];
            float Sn = pp[0][256 + t] + pp[1][256 + t] + pp[2][256 + t] + pp[3][256 + t];
            float z = sigm(gz + Sz);
            float r = sigm(gr + Sr);
            float n = tanh_f(gn + r * Sn);
            p_s[t] = hreg * xw;        // for deferred y_s
            hreg = (1.f - z) * n + z * hreg;
            h_s[t] = hreg;
        }
        __syncthreads();
    }
    // final deferred y (s = SS-1); last barrier already published p_s
    if (t >= 704) {
        int l = t - 704;
        float pv = p_s[l] + p_s[l + 64];
#pragma unroll
        for (int o = 32; o > 0; o >>= 1) pv += __shfl_xor(pv, o);
        if (l == 0) omain[SS - 1] = sigm(pv + beo);
    }
}

// ---------------------------------------------------------------------------
extern "C" void kernel_launch(void* const* d_in, const int* in_sizes, int n_in,
                              void* d_out, int out_size, void* d_ws, size_t ws_size,
                              hipStream_t stream) {
    const int* in_e   = (const int*)d_in[0];
    const int* in_ed  = (const int*)d_in[1];
    const int* in_ep  = (const int*)d_in[2];
    const int* in_a   = (const int*)d_in[3];
    const int* in_as  = (const int*)d_in[4];
    const int* in_ha  = (const int*)d_in[5];
    const int* in_ca  = (const int*)d_in[6];
    const int* in_it  = (const int*)d_in[7];
    const float* deliver_h = (const float*)d_in[8];
    const int* pair_v = (const int*)d_in[9];
    const int* pair_e = (const int*)d_in[10];
    const int* ec_map = (const int*)d_in[11];
    const int* ecd_map= (const int*)d_in[12];
    const float* e_table  = (const float*)d_in[13];
    const float* c_table  = (const float*)d_in[14];
    const float* ed_table = (const float*)d_in[15];
    const float* cd_table = (const float*)d_in[16];
    const float* a_table  = (const float*)d_in[17];
    const float* it_table = (const float*)d_in[18];
    const float* ep_table = (const float*)d_in[19];
    const float* ha_table = (const float*)d_in[20];
    const float* ca_table = (const float*)d_in[21];
    const float* as_table = (const float*)d_in[22];
    const float* W1 = (const float*)d_in[23];
    const float* b1 = (const float*)d_in[24];
    const float* g1 = (const float*)d_in[25];
    const float* be1= (const float*)d_in[26];
    const float* m1 = (const float*)d_in[27];
    const float* v1 = (const float*)d_in[28];
    const float* W2 = (const float*)d_in[29];
    const float* b2 = (const float*)d_in[30];
    const float* g2 = (const float*)d_in[31];
    const float* be2= (const float*)d_in[32];
    const float* m2 = (const float*)d_in[33];
    const float* v2 = (const float*)d_in[34];
    const float* Wi = (const float*)d_in[35];
    const float* bi = (const float*)d_in[36];
    const float* Wg = (const float*)d_in[37];
    const float* Ug = (const float*)d_in[38];
    const float* bg = (const float*)d_in[39];
    const float* We = (const float*)d_in[40];
    const float* beo= (const float*)d_in[41];
    const float* Ws = (const float*)d_in[42];
    const float* bs = (const float*)d_in[43];
    float* out = (float*)d_out;
    char* ws = (char*)d_ws;

    size_t off = 0;
    auto alloc = [&](size_t bytes) { size_t o = off; off += (bytes + 255) & ~(size_t)255; return o; };
    size_t o_degcur = alloc(378 * 4);            // e_deg[189] + cursor[189]
    size_t o_start  = alloc(190 * 4);
    size_t o_list   = alloc((size_t)NPAIR * 4);
    size_t o_aff    = alloc(512 * 4);
    size_t o_W1T    = alloc(16384 * 2);
    size_t o_W2T    = alloc(16384 * 2);
    size_t o_WiTe   = alloc(16384 * 2);
    size_t o_WgT    = alloc(49152 * 2);
    size_t o_UgT    = alloc(49152 * 2);
    size_t o_edW    = alloc(101 * 128 * 4);
    size_t o_epW    = alloc(101 * 128 * 4);
    size_t o_cW     = alloc(189 * 128 * 4);
    size_t o_cdW    = alloc(101 * 128 * 4);
    size_t o_agi    = alloc(2 * 384 * 4);
    size_t o_sd     = alloc(38 * 4);
    size_t o_etb    = alloc((size_t)N_V * DD * 2);
    size_t o_E      = alloc((size_t)N_HE * DD * 4);
    size_t o_Y      = alloc((size_t)N_V * DD * 4);
    size_t o_X1     = alloc((size_t)N_V * DD * 2);
    size_t o_X2     = alloc((size_t)N_V * DD * 2);
    size_t o_XW     = alloc((size_t)N_V * DD * 4);
    size_t o_xbf    = alloc((size_t)BSR * DD * 2);
    size_t o_gi     = alloc((size_t)BSR * 384 * 4);

    int*    e_deg  = (int*)(ws + o_degcur);
    int*    cursor = e_deg + 189;
    int*    startp = (int*)(ws + o_start);
    int*    listp  = (int*)(ws + o_list);
    float*  aff    = (float*)(ws + o_aff);
    ushort* W1T    = (ushort*)(ws + o_W1T);
    ushort* W2T    = (ushort*)(ws + o_W2T);
    ushort* WiTe   = (ushort*)(ws + o_WiTe);
    ushort* WgT    = (ushort*)(ws + o_WgT);
    ushort* UgTp   = (ushort*)(ws + o_UgT);
    float*  edW    = (float*)(ws + o_edW);
    float*  epW    = (float*)(ws + o_epW);
    float*  cW     = (float*)(ws + o_cW);
    float*  cdW    = (float*)(ws + o_cdW);
    float*  agi    = (float*)(ws + o_agi);
    float*  sd     = (float*)(ws + o_sd);
    ushort* e_tb   = (ushort*)(ws + o_etb);
    float*  E      = (float*)(ws + o_E);
    float*  Y      = (float*)(ws + o_Y);
    ushort* X1b    = (ushort*)(ws + o_X1);
    ushort* X2b    = (ushort*)(ws + o_X2);
    float*  XW     = (float*)(ws + o_XW);
    ushort* xbf    = (ushort*)(ws + o_xbf);
    float*  gi     = (float*)(ws + o_gi);

    hipMemsetAsync(ws + o_degcur, 0, 378 * 4, stream);

    P1Args pa;
    pa.pair_e = pair_e;
    pa.b1 = b1; pa.g1 = g1; pa.be1 = be1; pa.m1 = m1; pa.v1 = v1;
    pa.b2 = b2; pa.g2 = g2; pa.be2 = be2; pa.m2 = m2; pa.v2 = v2;
    pa.W1 = W1; pa.W2 = W2; pa.Wi = Wi; pa.Wg = Wg; pa.Ug = Ug;
    pa.ed_t = ed_table; pa.ep_t = ep_table; pa.c_t = c_table; pa.cd_t = cd_table;
    pa.a_t = a_table; pa.bi = bi; pa.bg = bg;
    pa.ha_t = ha_table; pa.ca_t = ca_table; pa.as_t = as_table; pa.it_t = it_table; pa.Ws = Ws;
    pa.e_deg = e_deg; pa.aff = aff;
    pa.W1T = W1T; pa.W2T = W2T; pa.WiTe = WiTe; pa.WgT = WgT; pa.UgT = UgTp;
    pa.edW = edW; pa.epW = epW; pa.cW = cW; pa.cdW = cdW; pa.agi = agi; pa.sd = sd;
    p1_kernel<<<1012, 384, 0, stream>>>(pa);

    cvt_kernel<<<(N_V * DD + 255) / 256, 256, 0, stream>>>(e_table, e_tb, N_V * DD);
    csr_prefix<<<1, 256, 0, stream>>>(e_deg, startp);
    csr_fill<<<94, 384, 0, stream>>>(pair_e, pair_v, startp, cursor, listp);

    pred_s_kernel<<<(BSR + 255) / 256, 256, 0, stream>>>(in_ha, in_ca, in_as, in_it, sd, bs, out);

    // conv1: Y = BN1(e_table @ W1 + b1)
    gemm_mfma<8><<<(N_V + 63) / 64, 256, 0, stream>>>(e_tb, W1T, Y, N_V, aff, aff + 128,
                                                      nullptr, nullptr);
    edge_mean<<<N_HE, 512, 0, stream>>>(Y, listp, startp, E);
    v_mean<<<(N_V * DD + 255) / 256, 256, 0, stream>>>(E, pair_e, X1b, 1);
    // conv2
    gemm_mfma<8><<<(N_V + 63) / 64, 256, 0, stream>>>(X1b, W2T, Y, N_V, aff + 256, aff + 384,
                                                      nullptr, nullptr);
    edge_mean<<<N_HE, 512, 0, stream>>>(Y, listp, startp, E);
    v_mean<<<(N_V * DD + 255) / 256, 256, 0, stream>>>(E, pair_e, X2b, 0);
    // XW = X2 @ Wi_e
    gemm_mfma<8><<<(N_V + 63) / 64, 256, 0, stream>>>(X2b, WiTe, XW, N_V, nullptr, nullptr,
                                                      nullptr, nullptr);
    // x = tanh(5-way gather sum)
    k3_kernel<<<(BSR * DD + 255) / 256, 256, 0, stream>>>(in_e, in_ed, in_ep, XW, cW, cdW, edW,
                                                          epW, ec_map, ecd_map, xbf);
    // gi = x @ Wg_x + a_gi[input_a]
    gemm_mfma<24><<<BSR / 64, 256, 0, stream>>>(xbf, WgT, gi, BSR, nullptr, nullptr, agi, in_a);
    // GRU scan + pred_main
    gru_scan<<<BB, 768, 0, stream>>>(gi, xbf, UgTp, deliver_h, We, beo, out);
}